// Round 3
// baseline (10.234 us; speedup 1.0000x reference)
//
#include <hip/hip_runtime.h>

// SmoothEmbedding: out[t,:] = w0*E[clip(i-1)] + w1*E[i] + w2*E[clip(i+1)],
// i = x[t]. The [N,N] banded smoothing matrix has 3 nonzeros/row, so the
// einsum collapses to a 3-row gather. Taps are hardcoded: the stored matrix
// values are exactly float32(0.15)/float32(0.7) (single np.add.at accumulation),
// identical to the 0.15f/0.7f literals; edge clipping reproduces the
// edge-row tap merging (w0+w1 on row 0, w1+w2 on row N-1).
//
// Round-3 variant: 2 tokens per 32-lane group (2048 waves, 512 WGs) for
// more memory-level parallelism and half the dispatch ramp; x read as int2.

namespace {

constexpr int kNEmbed = 4096;
constexpr int kDim    = 128;

__global__ __launch_bounds__(256) void smooth_embed_kernel(
    const int*   __restrict__ x,
    const float* __restrict__ table,    // [N_EMBED, 128] f32
    float*       __restrict__ out,      // [ntok, 128] f32
    int ntok)
{
    const int tid  = blockIdx.x * blockDim.x + threadIdx.x;
    const int g    = tid >> 5;          // 32-lane group: 2 tokens
    const int lane = tid & 31;
    const int d0   = lane << 2;         // 4 floats per lane
    const int t0   = g << 1;
    if (t0 >= ntok) return;

    const float w0 = 0.15f, w1 = 0.70f, w2 = 0.15f;

    // ntok is even (8192) and t0 is even -> 8B-aligned int2 load.
    const int2 xi = *(const int2*)(x + t0);
    const int ia  = xi.x;
    const int ib  = xi.y;

    const int iam = ia > 0 ? ia - 1 : 0;
    const int iap = ia < kNEmbed - 1 ? ia + 1 : kNEmbed - 1;
    const int ibm = ib > 0 ? ib - 1 : 0;
    const int ibp = ib < kNEmbed - 1 ? ib + 1 : kNEmbed - 1;

    // 6 independent row-gathers -> MLP; all L2-resident after first touch.
    const float4 a0 = *(const float4*)(table + (size_t)iam * kDim + d0);
    const float4 b0 = *(const float4*)(table + (size_t)ia  * kDim + d0);
    const float4 c0 = *(const float4*)(table + (size_t)iap * kDim + d0);
    const float4 a1 = *(const float4*)(table + (size_t)ibm * kDim + d0);
    const float4 b1 = *(const float4*)(table + (size_t)ib  * kDim + d0);
    const float4 c1 = *(const float4*)(table + (size_t)ibp * kDim + d0);

    float4 r0, r1;
    r0.x = w0 * a0.x + w1 * b0.x + w2 * c0.x;
    r0.y = w0 * a0.y + w1 * b0.y + w2 * c0.y;
    r0.z = w0 * a0.z + w1 * b0.z + w2 * c0.z;
    r0.w = w0 * a0.w + w1 * b0.w + w2 * c0.w;
    r1.x = w0 * a1.x + w1 * b1.x + w2 * c1.x;
    r1.y = w0 * a1.y + w1 * b1.y + w2 * c1.y;
    r1.z = w0 * a1.z + w1 * b1.z + w2 * c1.z;
    r1.w = w0 * a1.w + w1 * b1.w + w2 * c1.w;

    *(float4*)(out + (size_t)t0 * kDim + d0)       = r0;
    *(float4*)(out + (size_t)(t0 + 1) * kDim + d0) = r1;
}

} // namespace

extern "C" void kernel_launch(void* const* d_in, const int* in_sizes, int n_in,
                              void* d_out, int out_size, void* d_ws, size_t ws_size,
                              hipStream_t stream) {
    const int*   x     = (const int*)d_in[0];
    const float* table = (const float*)d_in[1];
    float*       out   = (float*)d_out;

    const int ntok   = in_sizes[0];                  // B*T = 8192 (even)
    const int groups = (ntok + 1) >> 1;              // 2 tokens per group
    const int threads = groups * 32;
    const int block   = 256;
    const int grid    = (threads + block - 1) / block;

    smooth_embed_kernel<<<grid, block, 0, stream>>>(x, table, out, ntok);
}

// Round 4
// 9.724 us; speedup vs baseline: 1.0524x; 1.0524x over previous
//
#include <hip/hip_runtime.h>

// SmoothEmbedding: out[t,:] = w0*E[clip(i-1)] + w1*E[i] + w2*E[clip(i+1)],
// i = x[t]. The [N,N] banded smoothing matrix has 3 nonzeros/row (taps
// 0.15/0.7/0.15, edge-clipped), so the [B,T,N]x[N,D] einsum collapses to a
// 3-row gather. Taps hardcoded: stored values are exactly float32(0.15)/
// float32(0.7) (single np.add.at accumulation), identical to the literals;
// index clipping reproduces the edge-row tap merging.
//
// Final form (round-2 organization, best measured): 1 token per 32-lane
// group, float4 per lane -> fully coalesced 512B row reads/writes. Measured
// end-to-end ~9.8 us is launch-overhead-bound: ideal traffic ~6 MB -> ~1 us
// device time; 2-tok/group variant (round 3) was neutral (10.2 us), so the
// fixed ~8-9 us dispatch overhead dominates and kernel-level changes are
// below the noise floor.

namespace {

constexpr int kNEmbed = 4096;
constexpr int kDim    = 128;

__global__ __launch_bounds__(256) void smooth_embed_kernel(
    const int*   __restrict__ x,
    const float* __restrict__ table,    // [N_EMBED, 128] f32
    float*       __restrict__ out,      // [ntok, 128] f32
    int ntok)
{
    const int tid   = blockIdx.x * blockDim.x + threadIdx.x;
    const int token = tid >> 5;          // 32 threads per token
    if (token >= ntok) return;
    const int d0    = (tid & 31) << 2;   // 4 floats per thread

    const float w0 = 0.15f, w1 = 0.70f, w2 = 0.15f;

    const int i  = x[token];
    const int im = i > 0 ? i - 1 : 0;
    const int ip = i < kNEmbed - 1 ? i + 1 : kNEmbed - 1;

    const float4 a = *(const float4*)(table + (size_t)im * kDim + d0);
    const float4 b = *(const float4*)(table + (size_t)i  * kDim + d0);
    const float4 c = *(const float4*)(table + (size_t)ip * kDim + d0);

    float4 r;
    r.x = w0 * a.x + w1 * b.x + w2 * c.x;
    r.y = w0 * a.y + w1 * b.y + w2 * c.y;
    r.z = w0 * a.z + w1 * b.z + w2 * c.z;
    r.w = w0 * a.w + w1 * b.w + w2 * c.w;

    *(float4*)(out + (size_t)token * kDim + d0) = r;
}

} // namespace

extern "C" void kernel_launch(void* const* d_in, const int* in_sizes, int n_in,
                              void* d_out, int out_size, void* d_ws, size_t ws_size,
                              hipStream_t stream) {
    const int*   x     = (const int*)d_in[0];
    const float* table = (const float*)d_in[1];
    float*       out   = (float*)d_out;

    const int ntok    = in_sizes[0];          // B*T = 8192
    const int threads = ntok * 32;            // 32 threads per token (float4 each)
    const int block   = 256;
    const int grid    = (threads + block - 1) / block;

    smooth_embed_kernel<<<grid, block, 0, stream>>>(x, table, out, ntok);
}